// Round 2
// baseline (652.455 us; speedup 1.0000x reference)
//
#include <hip/hip_runtime.h>
#include <math.h>

#define EPS 1e-5f

__device__ __forceinline__ float lrelu(float x){ return x >= 0.f ? x : 0.2f*x; }

// -----------------------------------------------------------------------------
// conv1x1 (256->64) + bias + InstanceNorm + LeakyReLU + spatial-mean centering.
// Output transposed for correlation: outT[n][p][co].
// grid = n*64 (one block per (n,co) row), block = 256.
__global__ void feat_kernel(const float* __restrict__ x,   // [n][256][4096]
                            const float* __restrict__ Wt,  // [64][256]
                            const float* __restrict__ bias,// [64]
                            float* __restrict__ outT)      // [n][4096][64]
{
    int blk = blockIdx.x;
    int n = blk >> 6, co = blk & 63;
    int tid = threadIdx.x;
    __shared__ float wrow[256];
    __shared__ float red[256];
    wrow[tid] = Wt[co*256 + tid];
    __syncthreads();
    const float* xb = x + (size_t)n*256*4096;
    float acc[16];
    #pragma unroll
    for (int k=0;k<16;k++) acc[k]=0.f;
    for (int ci=0; ci<256; ci++){
        float w = wrow[ci];
        const float* xr = xb + (size_t)ci*4096 + tid;
        #pragma unroll
        for (int k=0;k<16;k++) acc[k] += w * xr[k*256];
    }
    float b = bias[co];
    float s=0.f, s2=0.f;
    #pragma unroll
    for (int k=0;k<16;k++){ acc[k]+=b; s+=acc[k]; s2+=acc[k]*acc[k]; }
    red[tid]=s; __syncthreads();
    for (int o=128;o>0;o>>=1){ if(tid<o) red[tid]+=red[tid+o]; __syncthreads(); }
    float mean = red[0] * (1.f/4096.f); __syncthreads();
    red[tid]=s2; __syncthreads();
    for (int o=128;o>0;o>>=1){ if(tid<o) red[tid]+=red[tid+o]; __syncthreads(); }
    float var = red[0]*(1.f/4096.f) - mean*mean;
    float inv = rsqrtf(var + EPS);
    __syncthreads();
    float s3=0.f;
    #pragma unroll
    for (int k=0;k<16;k++){ acc[k] = lrelu((acc[k]-mean)*inv); s3+=acc[k]; }
    red[tid]=s3; __syncthreads();
    for (int o=128;o>0;o>>=1){ if(tid<o) red[tid]+=red[tid+o]; __syncthreads(); }
    float mean2 = red[0]*(1.f/4096.f);
    float* ob = outT + (size_t)n*4096*64 + co;
    #pragma unroll
    for (int k=0;k<16;k++){
        int p = tid + k*256;
        ob[(size_t)p*64] = acc[k]-mean2;
    }
}

// -----------------------------------------------------------------------------
// per-position channel L2 normalization in place: row /= (||row|| + EPS)
__global__ void posnorm_kernel(float* __restrict__ t) // [n*4096][64]
{
    int r = blockIdx.x*blockDim.x + threadIdx.x;
    float4* r4 = (float4*)(t + (size_t)r*64);
    float s = 0.f;
    float4 v[16];
    #pragma unroll
    for (int i=0;i<16;i++){ v[i]=r4[i]; s += v[i].x*v[i].x + v[i].y*v[i].y + v[i].z*v[i].z + v[i].w*v[i].w; }
    float inv = 1.f/(sqrtf(s)+EPS);
    #pragma unroll
    for (int i=0;i<16;i++){ v[i].x*=inv; v[i].y*=inv; v[i].z*=inv; v[i].w*=inv; r4[i]=v[i]; }
}

// -----------------------------------------------------------------------------
// generic 3x3 conv, Cin=Cout=3, pad=1 (reflect or zero), stride 1 or 2, +bias.
// Writes f32 conv output and per-(n,co) atomic sum/sumsq for InstanceNorm.
template<int STRIDE, bool REFLECT>
__global__ void conv3_kernel(const float* __restrict__ in_, int H, int Wd,
                             const float* __restrict__ wgt,
                             const float* __restrict__ bias,
                             float* __restrict__ out, float* __restrict__ sums)
{
    int oH = (H-1)/STRIDE + 1, oW = (Wd-1)/STRIDE + 1;
    int tid = threadIdx.x;
    size_t idx = (size_t)blockIdx.x*256 + tid;
    int ow = (int)(idx % oW); size_t t = idx / oW;
    int oh = (int)(t % oH); t /= oH;
    int co = (int)(t % 3); int n = (int)(t/3);
    float w[27];
    #pragma unroll
    for (int i=0;i<27;i++) w[i] = wgt[co*27 + i];
    float acc = bias[co];
    #pragma unroll
    for (int ci=0;ci<3;ci++){
        size_t base = ((size_t)(n*3+ci))*H*Wd;
        #pragma unroll
        for (int kh=0;kh<3;kh++){
            int ih = oh*STRIDE + kh - 1;
            if (REFLECT) ih = ih<0 ? -ih : (ih>=H ? 2*H-2-ih : ih);
            #pragma unroll
            for (int kw=0;kw<3;kw++){
                int iw = ow*STRIDE + kw - 1;
                if (REFLECT) iw = iw<0 ? -iw : (iw>=Wd ? 2*Wd-2-iw : iw);
                bool ok = REFLECT || (ih>=0 && ih<H && iw>=0 && iw<Wd);
                if (ok) acc += w[(ci*3+kh)*3+kw] * in_[base + (size_t)ih*Wd + iw];
            }
        }
    }
    out[idx] = acc;
    __shared__ float red[256];
    red[tid] = acc; __syncthreads();
    for (int o=128;o>0;o>>=1){ if(tid<o) red[tid]+=red[tid+o]; __syncthreads(); }
    float blockSum = red[0]; __syncthreads();
    red[tid] = acc*acc; __syncthreads();
    for (int o=128;o>0;o>>=1){ if(tid<o) red[tid]+=red[tid+o]; __syncthreads(); }
    if (tid==0){
        int pair = n*3+co;
        atomicAdd(&sums[pair*2],   blockSum);
        atomicAdd(&sums[pair*2+1], red[0]);
    }
}

// mean / inv-std per (n,c) pair from atomic sums. 6 pairs.
__global__ void instats_kernel(const float* __restrict__ sums, float* __restrict__ mstats, float cntInv)
{
    int i = threadIdx.x;
    if (i < 6){
        float m = sums[i*2]*cntInv;
        float v = sums[i*2+1]*cntInv - m*m;
        mstats[i*2]   = m;
        mstats[i*2+1] = rsqrtf(v + EPS);
    }
}

// apply IN + lrelu elementwise
__global__ void inapply_kernel(const float* __restrict__ in, const float* __restrict__ mstats,
                               int planeSize, float* __restrict__ out)
{
    size_t idx = (size_t)blockIdx.x*256 + threadIdx.x;
    int pair = (int)(idx / planeSize);
    float m = mstats[pair*2], inv = mstats[pair*2+1];
    out[idx] = lrelu((in[idx]-m)*inv);
}

// -----------------------------------------------------------------------------
// 2x bilinear upsample, align_corners=True semantics
__global__ void up2x_kernel(const float* __restrict__ in, int H, int Wd, float* __restrict__ out)
{
    int oH = 2*H, oW = 2*Wd;
    size_t idx = (size_t)blockIdx.x*256 + threadIdx.x;
    int ow = (int)(idx % oW); size_t t = idx/oW;
    int oh = (int)(t % oH); int pl = (int)(t/oH);
    float ph = (float)oh * (float)(H-1)  / (float)(oH-1);
    float pw = (float)ow * (float)(Wd-1) / (float)(oW-1);
    int i0 = (int)ph; int i1 = min(i0+1, H-1); float fh = ph - (float)i0;
    int j0 = (int)pw; int j1 = min(j0+1, Wd-1); float fw = pw - (float)j0;
    const float* p = in + (size_t)pl*H*Wd;
    float v00=p[(size_t)i0*Wd+j0], v01=p[(size_t)i0*Wd+j1];
    float v10=p[(size_t)i1*Wd+j0], v11=p[(size_t)i1*Wd+j1];
    float v0 = v00 + (v01-v00)*fw;
    float v1 = v10 + (v11-v10)*fw;
    out[idx] = v0 + (v1-v0)*fh;
}

// -----------------------------------------------------------------------------
// Correlation pass 1: u[p][q] = exp(100*dot(fb_p, fa_q) - 64) written
// unnormalized (f32, coalesced via LDS transpose tile). Column sums (over p)
// accumulated to SSUM[n][q] via one atomicAdd per (block, q).
// grid = n(2) x qtile(64) x psplit(4) = 512 blocks; block 256 = 64 ql x 4 s.
__global__ __launch_bounds__(256) void corr_kernel(
    const float* __restrict__ faT, const float* __restrict__ fbT,
    float* __restrict__ corr, float* __restrict__ SSUM)
{
    int blk = blockIdx.x;
    int ps = blk & 3; int t = blk >> 2;
    int qtile = t & 63; int n = t >> 6;
    int tid = threadIdx.x;
    int ql = tid & 63, s = tid >> 6;

    __shared__ float faS[64*68];   // fa tile, padded stride 68
    __shared__ float fbS[64*64];   // fb chunk
    __shared__ float uS [64*64];   // output transpose tile [p_local][ql]

    // stage fa tile (64 q rows) coalesced
    const float* faB = faT + ((size_t)n*4096 + qtile*64)*64;
    #pragma unroll
    for (int r=0;r<4;r++){
        int idx = tid + 256*r;
        int row = idx >> 4, col4 = idx & 15;
        ((float4*)(faS + row*68))[col4] = ((const float4*)(faB + row*64))[col4];
    }
    __syncthreads();
    float4 fr[16];
    #pragma unroll
    for (int i=0;i<16;i++) fr[i] = ((const float4*)(faS + ql*68))[i];

    const float* fbB = fbT + (size_t)n*4096*64;
    float* corrN = corr + (size_t)n*4096*4096 + qtile*64;
    float S = 0.f;

    for (int pc=0; pc<16; pc++){
        int p0 = (ps*16 + pc)*64;
        // stage fb chunk (64 p rows)
        const float4* src = (const float4*)(fbB + (size_t)p0*64);
        #pragma unroll
        for (int r=0;r<4;r++) ((float4*)fbS)[tid + 256*r] = src[tid + 256*r];
        __syncthreads();   // fbS ready; previous writeout done
        #pragma unroll
        for (int j=0;j<16;j++){
            int pl = s*16 + j;
            const float4* fl = (const float4*)(fbS + pl*64);
            float e = 0.f;
            #pragma unroll
            for (int i=0;i<16;i++){
                float4 fv = fl[i];
                float4 av = fr[i];
                e += fv.x*av.x + fv.y*av.y + fv.z*av.z + fv.w*av.w;
            }
            float u = __expf(fmaf(e, 100.f, -64.f));
            S += u;
            uS[pl*64 + ql] = u;
        }
        __syncthreads();   // uS complete
        // coalesced writeout: 64 p rows x 64 q
        #pragma unroll
        for (int r=0;r<4;r++){
            int idx = tid + 256*r;
            int row = idx >> 4, col4 = idx & 15;
            ((float4*)(corrN + (size_t)(p0+row)*4096))[col4] =
                ((const float4*)(uS + row*64))[col4];
        }
    }
    __syncthreads();
    fbS[tid] = S;
    __syncthreads();
    if (tid < 64){
        float Sq = fbS[tid] + fbS[64+tid] + fbS[128+tid] + fbS[192+tid];
        atomicAdd(SSUM + n*4096 + qtile*64 + tid, Sq);
    }
}

// invert the column sums
__global__ void inv_kernel(const float* __restrict__ SSUM, float* __restrict__ INVS)
{
    int i = blockIdx.x*256 + threadIdx.x;
    INVS[i] = 1.f / SSUM[i];
}

// -----------------------------------------------------------------------------
// Pass 2: corr *= invS (in place, f32, coalesced float4) and partial warp sums.
// grid = n(2) x qv(4) x pc(32) = 256 blocks; block 256; thread owns 4 q's.
__global__ __launch_bounds__(256) void warp_kernel(
    float* __restrict__ corr, const float* __restrict__ INVS,
    const float* __restrict__ fc,   // [n][3][4096]
    float* __restrict__ part)       // [pc][n][3][4096]
{
    int blk = blockIdx.x;
    int pc = blk & 31; int t = blk >> 5;
    int qv = t & 3; int n = t >> 2;
    int tid = threadIdx.x;

    __shared__ float fcS[3*128];
    if (tid < 96){
        int c = tid >> 5, off = (tid & 31)*4;
        ((float4*)(fcS + c*128))[tid & 31] =
            *((const float4*)(fc + (size_t)n*12288 + c*4096 + pc*128 + off));
    }
    __syncthreads();

    float4 inv4 = *((const float4*)(INVS + n*4096 + qv*1024 + tid*4));
    float4 a0 = {0,0,0,0}, a1 = {0,0,0,0}, a2 = {0,0,0,0};
    float* base = corr + (size_t)n*4096*4096 + (size_t)pc*128*4096 + qv*1024 + tid*4;
    for (int p=0; p<128; p++){
        float4* addr = (float4*)(base + (size_t)p*4096);
        float4 u = *addr;
        u.x *= inv4.x; u.y *= inv4.y; u.z *= inv4.z; u.w *= inv4.w;
        *addr = u;
        float f0 = fcS[p], f1 = fcS[128+p], f2 = fcS[256+p];
        a0.x += f0*u.x; a0.y += f0*u.y; a0.z += f0*u.z; a0.w += f0*u.w;
        a1.x += f1*u.x; a1.y += f1*u.y; a1.z += f1*u.z; a1.w += f1*u.w;
        a2.x += f2*u.x; a2.y += f2*u.y; a2.z += f2*u.z; a2.w += f2*u.w;
    }
    float* pb = part + (size_t)((pc*2 + n)*3)*4096 + qv*1024 + tid*4;
    *((float4*)(pb))         = a0;
    *((float4*)(pb + 4096))  = a1;
    *((float4*)(pb + 8192))  = a2;
}

// reduce the 32 p-chunk partials -> WARP[n][c][q]
__global__ void warpreduce_kernel(const float* __restrict__ part, float* __restrict__ warp)
{
    int idx = blockIdx.x*256 + threadIdx.x;   // < 24576 = 2*3*4096
    float s = 0.f;
    #pragma unroll
    for (int pc=0; pc<32; pc++) s += part[(size_t)pc*24576 + idx];
    warp[idx] = s;
}

// -----------------------------------------------------------------------------
extern "C" void kernel_launch(void* const* d_in, const int* in_sizes, int n_in,
                              void* d_out, int out_size, void* d_ws, size_t ws_size,
                              hipStream_t stream)
{
    const float* fa_raw = (const float*)d_in[0];
    const float* fb_raw = (const float*)d_in[1];
    const float* fc_raw = (const float*)d_in[2];
    const float* Wa  = (const float*)d_in[3];
    const float* ba  = (const float*)d_in[4];
    const float* Wb  = (const float*)d_in[5];
    const float* bb  = (const float*)d_in[6];
    const float* Wc1 = (const float*)d_in[7];
    const float* bc1 = (const float*)d_in[8];
    const float* Wc2 = (const float*)d_in[9];
    const float* bc2 = (const float*)d_in[10];
    const float* Wu1 = (const float*)d_in[11];
    const float* bu1 = (const float*)d_in[12];
    const float* Wu2 = (const float*)d_in[13];
    const float* bu2 = (const float*)d_in[14];

    float* ws    = (float*)d_ws;
    float* faT   = ws;                  // 524288
    float* fbT   = faT   + 524288;      // 524288
    float* CONV1 = fbT   + 524288;      // 98304  (2,3,128,128)
    float* FC64  = CONV1 + 98304;       // 24576  (2,3,64,64)
    float* UP1   = FC64  + 24576;       // 98304
    float* CONV2 = UP1   + 98304;       // 98304
    float* UP2   = CONV2 + 98304;       // 393216 (2,3,256,256)
    float* CONV3 = UP2   + 393216;      // 393216
    float* WARP  = CONV3 + 393216;      // 24576
    float* SSUM  = WARP  + 24576;       // 8192   [zeroed]
    float* SUMS  = SSUM  + 8192;        // 48     [zeroed]
    float* MST   = SUMS  + 48;          // 48
    float* INVS  = MST   + 48;          // 8192
    float* PART  = INVS  + 8192;        // 786432

    float* out_fc   = (float*)d_out;
    float* out_corr = out_fc + 393216;

    // zero the atomic accumulators (SSUM + SUMS, contiguous)
    hipMemsetAsync(SSUM, 0, (size_t)(8192 + 48)*sizeof(float), stream);

    // feature extractors
    feat_kernel<<<128,256,0,stream>>>(fa_raw, Wa, ba, faT);
    feat_kernel<<<128,256,0,stream>>>(fb_raw, Wb, bb, fbT);
    posnorm_kernel<<<32,256,0,stream>>>(faT);
    posnorm_kernel<<<32,256,0,stream>>>(fbT);

    // fc path: 256->128 (reflect, s2), 128->64 (reflect, s2)
    conv3_kernel<2,true><<<384,256,0,stream>>>(fc_raw, 256,256, Wc1, bc1, CONV1, SUMS+0);
    instats_kernel<<<1,64,0,stream>>>(SUMS+0,  MST+0,  1.f/16384.f);
    inapply_kernel<<<384,256,0,stream>>>(CONV1, MST+0,  16384, CONV1);
    conv3_kernel<2,true><<<96,256,0,stream>>>(CONV1, 128,128, Wc2, bc2, FC64, SUMS+12);
    instats_kernel<<<1,64,0,stream>>>(SUMS+12, MST+12, 4096 ? 1.f/4096.f : 0.f);
    inapply_kernel<<<96,256,0,stream>>>(FC64, MST+12, 4096, FC64);

    // correlation softmax + warp
    corr_kernel<<<512,256,0,stream>>>(faT, fbT, out_corr, SSUM);
    inv_kernel<<<32,256,0,stream>>>(SSUM, INVS);
    warp_kernel<<<256,256,0,stream>>>(out_corr, INVS, FC64, PART);
    warpreduce_kernel<<<96,256,0,stream>>>(PART, WARP);

    // upsample block 1: 64 -> 128
    up2x_kernel<<<384,256,0,stream>>>(WARP, 64,64, UP1);
    conv3_kernel<1,false><<<384,256,0,stream>>>(UP1, 128,128, Wu1, bu1, CONV2, SUMS+24);
    instats_kernel<<<1,64,0,stream>>>(SUMS+24, MST+24, 1.f/16384.f);
    inapply_kernel<<<384,256,0,stream>>>(CONV2, MST+24, 16384, CONV2);

    // upsample block 2: 128 -> 256, final output
    up2x_kernel<<<1536,256,0,stream>>>(CONV2, 128,128, UP2);
    conv3_kernel<1,false><<<1536,256,0,stream>>>(UP2, 256,256, Wu2, bu2, CONV3, SUMS+36);
    instats_kernel<<<1,64,0,stream>>>(SUMS+36, MST+36, 1.f/65536.f);
    inapply_kernel<<<1536,256,0,stream>>>(CONV3, MST+36, 65536, out_fc);
}

// Round 3
// 515.169 us; speedup vs baseline: 1.2665x; 1.2665x over previous
//
#include <hip/hip_runtime.h>
#include <math.h>

#define EPS 1e-5f

typedef short short8 __attribute__((ext_vector_type(8)));
typedef __bf16 bf16x8 __attribute__((ext_vector_type(8)));
typedef float f32x4  __attribute__((ext_vector_type(4)));

__device__ __forceinline__ float lrelu(float x){ return x >= 0.f ? x : 0.2f*x; }

// round-to-nearest-even f32 -> bf16 bits
__device__ __forceinline__ short f2bf_s(float x){
    unsigned u = __float_as_uint(x);
    unsigned r = (u + 0x7FFFu + ((u >> 16) & 1u)) >> 16;
    return (short)r;
}
__device__ __forceinline__ float bfs2f(short h){
    return __uint_as_float(((unsigned)(unsigned short)h) << 16);
}

__device__ __forceinline__ f32x4 mfma16(bf16x8 a, bf16x8 b, f32x4 c){
    return __builtin_amdgcn_mfma_f32_16x16x32_bf16(a, b, c, 0, 0, 0);
}

// -----------------------------------------------------------------------------
// conv1x1 (256->64) + bias + InstanceNorm + LeakyReLU + spatial-mean centering.
// Output transposed for correlation: outT[n][p][co].
__global__ void feat_kernel(const float* __restrict__ x,   // [n][256][4096]
                            const float* __restrict__ Wt,  // [64][256]
                            const float* __restrict__ bias,// [64]
                            float* __restrict__ outT)      // [n][4096][64]
{
    int blk = blockIdx.x;
    int n = blk >> 6, co = blk & 63;
    int tid = threadIdx.x;
    __shared__ float wrow[256];
    __shared__ float red[256];
    wrow[tid] = Wt[co*256 + tid];
    __syncthreads();
    const float* xb = x + (size_t)n*256*4096;
    float acc[16];
    #pragma unroll
    for (int k=0;k<16;k++) acc[k]=0.f;
    for (int ci=0; ci<256; ci++){
        float w = wrow[ci];
        const float* xr = xb + (size_t)ci*4096 + tid;
        #pragma unroll
        for (int k=0;k<16;k++) acc[k] += w * xr[k*256];
    }
    float b = bias[co];
    float s=0.f, s2=0.f;
    #pragma unroll
    for (int k=0;k<16;k++){ acc[k]+=b; s+=acc[k]; s2+=acc[k]*acc[k]; }
    red[tid]=s; __syncthreads();
    for (int o=128;o>0;o>>=1){ if(tid<o) red[tid]+=red[tid+o]; __syncthreads(); }
    float mean = red[0] * (1.f/4096.f); __syncthreads();
    red[tid]=s2; __syncthreads();
    for (int o=128;o>0;o>>=1){ if(tid<o) red[tid]+=red[tid+o]; __syncthreads(); }
    float var = red[0]*(1.f/4096.f) - mean*mean;
    float inv = rsqrtf(var + EPS);
    __syncthreads();
    float s3=0.f;
    #pragma unroll
    for (int k=0;k<16;k++){ acc[k] = lrelu((acc[k]-mean)*inv); s3+=acc[k]; }
    red[tid]=s3; __syncthreads();
    for (int o=128;o>0;o>>=1){ if(tid<o) red[tid]+=red[tid+o]; __syncthreads(); }
    float mean2 = red[0]*(1.f/4096.f);
    float* ob = outT + (size_t)n*4096*64 + co;
    #pragma unroll
    for (int k=0;k<16;k++){
        int p = tid + k*256;
        ob[(size_t)p*64] = acc[k]-mean2;
    }
}

// -----------------------------------------------------------------------------
// per-position channel L2 normalization in place
__global__ void posnorm_kernel(float* __restrict__ t) // [n*4096][64]
{
    int r = blockIdx.x*blockDim.x + threadIdx.x;
    float4* r4 = (float4*)(t + (size_t)r*64);
    float s = 0.f;
    float4 v[16];
    #pragma unroll
    for (int i=0;i<16;i++){ v[i]=r4[i]; s += v[i].x*v[i].x + v[i].y*v[i].y + v[i].z*v[i].z + v[i].w*v[i].w; }
    float inv = 1.f/(sqrtf(s)+EPS);
    #pragma unroll
    for (int i=0;i<16;i++){ v[i].x*=inv; v[i].y*=inv; v[i].z*=inv; v[i].w*=inv; r4[i]=v[i]; }
}

// -----------------------------------------------------------------------------
// generic 3x3 conv, Cin=Cout=3
template<int STRIDE, bool REFLECT>
__global__ void conv3_kernel(const float* __restrict__ in_, int H, int Wd,
                             const float* __restrict__ wgt,
                             const float* __restrict__ bias,
                             float* __restrict__ out, float* __restrict__ sums)
{
    int oH = (H-1)/STRIDE + 1, oW = (Wd-1)/STRIDE + 1;
    int tid = threadIdx.x;
    size_t idx = (size_t)blockIdx.x*256 + tid;
    int ow = (int)(idx % oW); size_t t = idx / oW;
    int oh = (int)(t % oH); t /= oH;
    int co = (int)(t % 3); int n = (int)(t/3);
    float w[27];
    #pragma unroll
    for (int i=0;i<27;i++) w[i] = wgt[co*27 + i];
    float acc = bias[co];
    #pragma unroll
    for (int ci=0;ci<3;ci++){
        size_t base = ((size_t)(n*3+ci))*H*Wd;
        #pragma unroll
        for (int kh=0;kh<3;kh++){
            int ih = oh*STRIDE + kh - 1;
            if (REFLECT) ih = ih<0 ? -ih : (ih>=H ? 2*H-2-ih : ih);
            #pragma unroll
            for (int kw=0;kw<3;kw++){
                int iw = ow*STRIDE + kw - 1;
                if (REFLECT) iw = iw<0 ? -iw : (iw>=Wd ? 2*Wd-2-iw : iw);
                bool ok = REFLECT || (ih>=0 && ih<H && iw>=0 && iw<Wd);
                if (ok) acc += w[(ci*3+kh)*3+kw] * in_[base + (size_t)ih*Wd + iw];
            }
        }
    }
    out[idx] = acc;
    __shared__ float red[256];
    red[tid] = acc; __syncthreads();
    for (int o=128;o>0;o>>=1){ if(tid<o) red[tid]+=red[tid+o]; __syncthreads(); }
    float blockSum = red[0]; __syncthreads();
    red[tid] = acc*acc; __syncthreads();
    for (int o=128;o>0;o>>=1){ if(tid<o) red[tid]+=red[tid+o]; __syncthreads(); }
    if (tid==0){
        int pair = n*3+co;
        atomicAdd(&sums[pair*2],   blockSum);
        atomicAdd(&sums[pair*2+1], red[0]);
    }
}

__global__ void instats_kernel(const float* __restrict__ sums, float* __restrict__ mstats, float cntInv)
{
    int i = threadIdx.x;
    if (i < 6){
        float m = sums[i*2]*cntInv;
        float v = sums[i*2+1]*cntInv - m*m;
        mstats[i*2]   = m;
        mstats[i*2+1] = rsqrtf(v + EPS);
    }
}

__global__ void inapply_kernel(const float* __restrict__ in, const float* __restrict__ mstats,
                               int planeSize, float* __restrict__ out)
{
    size_t idx = (size_t)blockIdx.x*256 + threadIdx.x;
    int pair = (int)(idx / planeSize);
    float m = mstats[pair*2], inv = mstats[pair*2+1];
    out[idx] = lrelu((in[idx]-m)*inv);
}

// -----------------------------------------------------------------------------
__global__ void up2x_kernel(const float* __restrict__ in, int H, int Wd, float* __restrict__ out)
{
    int oH = 2*H, oW = 2*Wd;
    size_t idx = (size_t)blockIdx.x*256 + threadIdx.x;
    int ow = (int)(idx % oW); size_t t = idx/oW;
    int oh = (int)(t % oH); int pl = (int)(t/oH);
    float ph = (float)oh * (float)(H-1)  / (float)(oH-1);
    float pw = (float)ow * (float)(Wd-1) / (float)(oW-1);
    int i0 = (int)ph; int i1 = min(i0+1, H-1); float fh = ph - (float)i0;
    int j0 = (int)pw; int j1 = min(j0+1, Wd-1); float fw = pw - (float)j0;
    const float* p = in + (size_t)pl*H*Wd;
    float v00=p[(size_t)i0*Wd+j0], v01=p[(size_t)i0*Wd+j1];
    float v10=p[(size_t)i1*Wd+j0], v11=p[(size_t)i1*Wd+j1];
    float v0 = v00 + (v01-v00)*fw;
    float v1 = v10 + (v11-v10)*fw;
    out[idx] = v0 + (v1-v0)*fh;
}

// -----------------------------------------------------------------------------
// MFMA correlation. e[p][q] = dot(fb_p, fa_q) via 3-term bf16 split
// (hi*hi + hi*lo + lo*hi), u = exp(100e - 64).
// PASS 0: accumulate per-q column sums S into SSUM (atomic).
// PASS 1: recompute u (identical MFMA order -> identical bits), write
//         P = u * INVS[q] to corr, and fuse warp partials (3 ch) via
//         quad-shuffle reduce + atomicAdd into WARP.
// grid = n(2) x pb(32) x qb(32) = 2048; block 256 = 4 waves in 2x2;
// wave tile 64x64 = 4x4 MFMA 16x16 tiles, K=64.
// LDS 64KB: fragment-ordered bf16 hi/lo chunks for fb (p rows) and fa (q rows).
template<int PASS>
__global__ __launch_bounds__(256,2) void corr_mfma(
    const float* __restrict__ faT, const float* __restrict__ fbT,
    float* __restrict__ corr, float* __restrict__ SSUM,
    const float* __restrict__ INVS,
    const float* __restrict__ fc, float* __restrict__ WARP)
{
    __shared__ short lds[32768];   // 64KB: fb_hi|fb_lo|fa_hi|fa_lo, 8192 each

    int blk = blockIdx.x;
    int qb = blk & 31, pb = (blk >> 5) & 31, n = blk >> 10;
    int tid = threadIdx.x;

    // ---- stage + convert f32 -> bf16 hi/lo, fragment-ordered chunks ----
    // chunk idx layout (per side/prec): addr16 = idx, where
    // idx = (g*8 + c)*16 + r ; global row = g*16 + r ; k-bytes chunk c (8 elems)
    const float* faB = faT + ((size_t)n*4096 + (size_t)qb*128)*64;
    const float* fbB = fbT + ((size_t)n*4096 + (size_t)pb*128)*64;
    #pragma unroll
    for (int it=0; it<8; it++){
        int cid = it*256 + tid;        // [0,2048)
        int side = cid >> 10;          // 0 fb, 1 fa
        int idx  = cid & 1023;
        int r = idx & 15, c = (idx>>4)&7, g = idx>>7;
        int grow = g*16 + r;
        const float* src = (side ? faB : fbB) + grow*64 + c*8;
        float4 x0 = *(const float4*)src;
        float4 x1 = *(const float4*)(src+4);
        float xs[8] = {x0.x,x0.y,x0.z,x0.w,x1.x,x1.y,x1.z,x1.w};
        short8 h, l;
        #pragma unroll
        for (int j=0;j<8;j++){
            short hh = f2bf_s(xs[j]);
            h[j] = hh;
            l[j] = f2bf_s(xs[j] - bfs2f(hh));
        }
        int base16 = side*16384;
        *(short8*)(lds + base16 + idx*8)        = h;
        *(short8*)(lds + base16 + 8192 + idx*8) = l;
    }
    __syncthreads();

    int wave = tid >> 6, lane = tid & 63;
    int wp = wave >> 1, wq = wave & 1;
    int quad = lane >> 4, l16 = lane & 15;

    f32x4 acc[4][4];
    #pragma unroll
    for (int pt=0;pt<4;pt++)
        #pragma unroll
        for (int qt=0;qt<4;qt++)
            acc[pt][qt] = (f32x4){0.f,0.f,0.f,0.f};

    #pragma unroll
    for (int kc=0;kc<2;kc++){
        int cc = kc*4 + quad;
        bf16x8 Ah[4], Al[4], Bh[4], Bl[4];
        #pragma unroll
        for (int t4=0;t4<4;t4++){
            int offA = (((wp*4+t4)*8 + cc)*16 + l16)*8;
            Ah[t4] = (bf16x8)(*(const short8*)(lds + offA));
            Al[t4] = (bf16x8)(*(const short8*)(lds + 8192 + offA));
            int offB = 16384 + (((wq*4+t4)*8 + cc)*16 + l16)*8;
            Bh[t4] = (bf16x8)(*(const short8*)(lds + offB));
            Bl[t4] = (bf16x8)(*(const short8*)(lds + 8192 + offB));
        }
        #pragma unroll
        for (int pt=0;pt<4;pt++)
            #pragma unroll
            for (int qt=0;qt<4;qt++){
                acc[pt][qt] = mfma16(Ah[pt], Bh[qt], acc[pt][qt]);
                acc[pt][qt] = mfma16(Ah[pt], Bl[qt], acc[pt][qt]);
                acc[pt][qt] = mfma16(Al[pt], Bh[qt], acc[pt][qt]);
            }
    }

    if (PASS == 0){
        float colsum[4] = {0.f,0.f,0.f,0.f};
        #pragma unroll
        for (int pt=0;pt<4;pt++)
            #pragma unroll
            for (int qt=0;qt<4;qt++)
                #pragma unroll
                for (int i=0;i<4;i++)
                    colsum[qt] += __expf(fmaf(acc[pt][qt][i], 100.f, -64.f));
        #pragma unroll
        for (int qt=0;qt<4;qt++){
            float v = colsum[qt];
            v += __shfl_xor(v, 16);
            v += __shfl_xor(v, 32);
            if (lane < 16)
                atomicAdd(&SSUM[n*4096 + qb*128 + wq*64 + qt*16 + lane], v);
        }
    } else {
        float inv4[4];
        int qoff = n*4096 + qb*128 + wq*64 + l16;
        #pragma unroll
        for (int qt=0;qt<4;qt++) inv4[qt] = INVS[qoff + qt*16];
        float wa0[4]={0,0,0,0}, wa1[4]={0,0,0,0}, wa2[4]={0,0,0,0};
        const float* fcb = fc + (size_t)n*12288;
        float* corrN = corr + (size_t)n*4096*4096;
        #pragma unroll
        for (int pt=0;pt<4;pt++){
            #pragma unroll
            for (int i=0;i<4;i++){
                int p = pb*128 + wp*64 + pt*16 + quad*4 + i;
                float f0 = fcb[p], f1 = fcb[4096+p], f2 = fcb[8192+p];
                float* rowp = corrN + (size_t)p*4096 + qb*128 + wq*64 + l16;
                #pragma unroll
                for (int qt=0;qt<4;qt++){
                    float u = __expf(fmaf(acc[pt][qt][i], 100.f, -64.f)) * inv4[qt];
                    rowp[qt*16] = u;
                    wa0[qt] += f0*u; wa1[qt] += f1*u; wa2[qt] += f2*u;
                }
            }
        }
        #pragma unroll
        for (int qt=0;qt<4;qt++){
            float v0 = wa0[qt], v1 = wa1[qt], v2 = wa2[qt];
            v0 += __shfl_xor(v0,16); v0 += __shfl_xor(v0,32);
            v1 += __shfl_xor(v1,16); v1 += __shfl_xor(v1,32);
            v2 += __shfl_xor(v2,16); v2 += __shfl_xor(v2,32);
            if (lane < 16){
                int q = qb*128 + wq*64 + qt*16 + lane;
                atomicAdd(&WARP[(size_t)n*12288 +        q], v0);
                atomicAdd(&WARP[(size_t)n*12288 + 4096 + q], v1);
                atomicAdd(&WARP[(size_t)n*12288 + 8192 + q], v2);
            }
        }
    }
}

__global__ void inv_kernel(const float* __restrict__ SSUM, float* __restrict__ INVS)
{
    int i = blockIdx.x*256 + threadIdx.x;
    INVS[i] = 1.f / SSUM[i];
}

// -----------------------------------------------------------------------------
extern "C" void kernel_launch(void* const* d_in, const int* in_sizes, int n_in,
                              void* d_out, int out_size, void* d_ws, size_t ws_size,
                              hipStream_t stream)
{
    const float* fa_raw = (const float*)d_in[0];
    const float* fb_raw = (const float*)d_in[1];
    const float* fc_raw = (const float*)d_in[2];
    const float* Wa  = (const float*)d_in[3];
    const float* ba  = (const float*)d_in[4];
    const float* Wb  = (const float*)d_in[5];
    const float* bb  = (const float*)d_in[6];
    const float* Wc1 = (const float*)d_in[7];
    const float* bc1 = (const float*)d_in[8];
    const float* Wc2 = (const float*)d_in[9];
    const float* bc2 = (const float*)d_in[10];
    const float* Wu1 = (const float*)d_in[11];
    const float* bu1 = (const float*)d_in[12];
    const float* Wu2 = (const float*)d_in[13];
    const float* bu2 = (const float*)d_in[14];

    float* ws    = (float*)d_ws;
    float* faT   = ws;                  // 524288
    float* fbT   = faT   + 524288;      // 524288
    float* CONV1 = fbT   + 524288;      // 98304
    float* FC64  = CONV1 + 98304;       // 24576
    float* UP1   = FC64  + 24576;       // 98304
    float* CONV2 = UP1   + 98304;       // 98304
    float* UP2   = CONV2 + 98304;       // 393216
    float* CONV3 = UP2   + 393216;      // 393216
    float* SSUM  = CONV3 + 393216;      // 8192   [zeroed]
    float* SUMS  = SSUM  + 8192;        // 48     [zeroed]
    float* WARP  = SUMS  + 48;          // 24576  [zeroed]
    float* MST   = WARP  + 24576;       // 48
    float* INVS  = MST   + 48;          // 8192

    float* out_fc   = (float*)d_out;
    float* out_corr = out_fc + 393216;

    // zero the atomic accumulators (SSUM+SUMS+WARP contiguous)
    hipMemsetAsync(SSUM, 0, (size_t)(8192 + 48 + 24576)*sizeof(float), stream);

    // feature extractors
    feat_kernel<<<128,256,0,stream>>>(fa_raw, Wa, ba, faT);
    feat_kernel<<<128,256,0,stream>>>(fb_raw, Wb, bb, fbT);
    posnorm_kernel<<<32,256,0,stream>>>(faT);
    posnorm_kernel<<<32,256,0,stream>>>(fbT);

    // fc path: 256->128 (reflect, s2), 128->64 (reflect, s2)
    conv3_kernel<2,true><<<384,256,0,stream>>>(fc_raw, 256,256, Wc1, bc1, CONV1, SUMS+0);
    instats_kernel<<<1,64,0,stream>>>(SUMS+0,  MST+0,  1.f/16384.f);
    inapply_kernel<<<384,256,0,stream>>>(CONV1, MST+0,  16384, CONV1);
    conv3_kernel<2,true><<<96,256,0,stream>>>(CONV1, 128,128, Wc2, bc2, FC64, SUMS+12);
    instats_kernel<<<1,64,0,stream>>>(SUMS+12, MST+12, 1.f/4096.f);
    inapply_kernel<<<96,256,0,stream>>>(FC64, MST+12, 4096, FC64);

    // correlation softmax (two-pass MFMA recompute) + fused warp
    corr_mfma<0><<<2048,256,0,stream>>>(faT, fbT, out_corr, SSUM, INVS, FC64, WARP);
    inv_kernel<<<32,256,0,stream>>>(SSUM, INVS);
    corr_mfma<1><<<2048,256,0,stream>>>(faT, fbT, out_corr, SSUM, INVS, FC64, WARP);

    // upsample block 1: 64 -> 128
    up2x_kernel<<<384,256,0,stream>>>(WARP, 64,64, UP1);
    conv3_kernel<1,false><<<384,256,0,stream>>>(UP1, 128,128, Wu1, bu1, CONV2, SUMS+24);
    instats_kernel<<<1,64,0,stream>>>(SUMS+24, MST+24, 1.f/16384.f);
    inapply_kernel<<<384,256,0,stream>>>(CONV2, MST+24, 16384, CONV2);

    // upsample block 2: 128 -> 256, final output
    up2x_kernel<<<1536,256,0,stream>>>(CONV2, 128,128, UP2);
    conv3_kernel<1,false><<<1536,256,0,stream>>>(UP2, 256,256, Wu2, bu2, CONV3, SUMS+36);
    instats_kernel<<<1,64,0,stream>>>(SUMS+36, MST+36, 1.f/65536.f);
    inapply_kernel<<<1536,256,0,stream>>>(CONV3, MST+36, 65536, out_fc);
}

// Round 4
// 401.019 us; speedup vs baseline: 1.6270x; 1.2847x over previous
//
#include <hip/hip_runtime.h>
#include <math.h>

#define EPS 1e-5f

typedef short short8 __attribute__((ext_vector_type(8)));
typedef __bf16 bf16x8 __attribute__((ext_vector_type(8)));
typedef float f32x4  __attribute__((ext_vector_type(4)));

__device__ __forceinline__ float lrelu(float x){ return x >= 0.f ? x : 0.2f*x; }

// round-to-nearest-even f32 -> bf16 bits
__device__ __forceinline__ short f2bf_s(float x){
    unsigned u = __float_as_uint(x);
    unsigned r = (u + 0x7FFFu + ((u >> 16) & 1u)) >> 16;
    return (short)r;
}
__device__ __forceinline__ float bfs2f(short h){
    return __uint_as_float(((unsigned)(unsigned short)h) << 16);
}

__device__ __forceinline__ f32x4 mfma16(bf16x8 a, bf16x8 b, f32x4 c){
    return __builtin_amdgcn_mfma_f32_16x16x32_bf16(a, b, c, 0, 0, 0);
}

// -----------------------------------------------------------------------------
// Feature path phase A: conv1x1 (256->64) + bias, both sides (fa,fb) in one
// launch, LDS-tiled, coalesced. Per-(side,n,co) sum/sumsq via wave-shuffle
// reduce + atomics. Y layout: [side][n][p][co].
// grid = 256 = side(2) x n(2) x pchunk(64 of 64 p); block 256 = 64 p x 4 cog.
__global__ __launch_bounds__(256,2) void feat_conv(
    const float* __restrict__ fa_raw, const float* __restrict__ fb_raw,
    const float* __restrict__ Wa, const float* __restrict__ Wb,
    const float* __restrict__ ba, const float* __restrict__ bb,
    float* __restrict__ Y, float* __restrict__ FSUM)   // FSUM[4*64][2]
{
    __shared__ float wS[256*65];   // W transposed [ci][co], pad 65
    __shared__ float xS[16*64];    // x tile [ci_l][p]

    int blk = blockIdx.x;
    int pch = blk & 63, n = (blk>>6)&1, side = blk>>7;
    int p0 = pch*64;
    const float* x    = (side ? fb_raw : fa_raw) + (size_t)n*256*4096 + p0;
    const float* W    = side ? Wb : Wa;
    const float* bias = side ? bb : ba;
    int tid = threadIdx.x;

    #pragma unroll
    for (int it=0; it<64; it++){
        int idx = it*256 + tid;
        int co = idx >> 8, ci = idx & 255;
        wS[ci*65 + co] = W[idx];
    }

    int pl = tid & 63, cog = tid >> 6;
    float acc[16];
    #pragma unroll
    for (int j=0;j<16;j++) acc[j] = 0.f;

    for (int cb=0; cb<16; cb++){
        __syncthreads();
        #pragma unroll
        for (int it=0; it<4; it++){
            int idx = it*256 + tid;
            int cl = idx >> 6, pp = idx & 63;
            xS[idx] = x[(size_t)(cb*16+cl)*4096 + pp];
        }
        __syncthreads();
        #pragma unroll
        for (int cl=0; cl<16; cl++){
            float xr = xS[cl*64 + pl];
            const float* wr = &wS[(cb*16+cl)*65 + cog*16];
            #pragma unroll
            for (int j=0;j<16;j++) acc[j] = fmaf(xr, wr[j], acc[j]);
        }
    }

    int pair = side*2 + n;
    #pragma unroll
    for (int j=0;j<16;j++){
        acc[j] += bias[cog*16+j];
        float v = acc[j], v2 = v*v;
        #pragma unroll
        for (int off=1; off<64; off<<=1){
            v  += __shfl_xor(v,  off);
            v2 += __shfl_xor(v2, off);
        }
        if (pl == 0){
            atomicAdd(&FSUM[(pair*64 + cog*16 + j)*2],   v);
            atomicAdd(&FSUM[(pair*64 + cog*16 + j)*2+1], v2);
        }
    }

    float* yr = Y + ((size_t)pair*4096 + p0 + pl)*64 + cog*16;
    #pragma unroll
    for (int j4=0;j4<4;j4++)
        *(float4*)(yr + j4*4) = make_float4(acc[j4*4],acc[j4*4+1],acc[j4*4+2],acc[j4*4+3]);
}

// mean / rstd per channel (256 = 4 pairs x 64 co)
__global__ void fstats_kernel(const float* __restrict__ FSUM, float* __restrict__ FST)
{
    int ch = threadIdx.x;
    float m = FSUM[ch*2] * (1.f/4096.f);
    float v = FSUM[ch*2+1] * (1.f/4096.f) - m*m;
    FST[ch*2]   = m;
    FST[ch*2+1] = rsqrtf(v + EPS);
}

// Phase C: y = lrelu((y-m)*rstd) in place + per-channel sums for re-centering.
// grid = 512 blocks x 64 rows each.
__global__ __launch_bounds__(256) void feat_apply(
    float* __restrict__ Y, const float* __restrict__ FST, float* __restrict__ M2SUM)
{
    __shared__ float red[256];
    int tid = threadIdx.x;
    size_t base = (size_t)blockIdx.x*4096;
    int pair = (int)(base >> 18);          // 4096*64 elems per pair-plane... (base/262144)
    int co = tid & 63;
    float m   = FST[(pair*64+co)*2];
    float inv = FST[(pair*64+co)*2+1];
    float asum = 0.f;
    #pragma unroll
    for (int it=0; it<16; it++){
        size_t idx = base + it*256 + tid;
        float y2 = lrelu((Y[idx]-m)*inv);
        Y[idx] = y2;
        asum += y2;
    }
    red[tid] = asum; __syncthreads();
    if (tid < 64)
        atomicAdd(&M2SUM[pair*64 + tid], red[tid]+red[tid+64]+red[tid+128]+red[tid+192]);
}

// Phase E: per-position: subtract spatial mean, L2-normalize over channels.
// one thread per (side,n,p) row; 16384 threads.
__global__ void feat_finish(float* __restrict__ Y, const float* __restrict__ M2SUM)
{
    int r = blockIdx.x*256 + threadIdx.x;
    int pair = r >> 12;
    const float4* m4 = (const float4*)(M2SUM + pair*64);
    float4* r4 = (float4*)(Y + (size_t)r*64);
    float s = 0.f;
    float4 v[16];
    #pragma unroll
    for (int i=0;i<16;i++){
        float4 t = r4[i], mm = m4[i];
        t.x -= mm.x*(1.f/4096.f); t.y -= mm.y*(1.f/4096.f);
        t.z -= mm.z*(1.f/4096.f); t.w -= mm.w*(1.f/4096.f);
        v[i] = t;
        s += t.x*t.x + t.y*t.y + t.z*t.z + t.w*t.w;
    }
    float inv = 1.f/(sqrtf(s)+EPS);
    #pragma unroll
    for (int i=0;i<16;i++){ v[i].x*=inv; v[i].y*=inv; v[i].z*=inv; v[i].w*=inv; r4[i]=v[i]; }
}

// -----------------------------------------------------------------------------
// generic 3x3 conv, Cin=Cout=3
template<int STRIDE, bool REFLECT>
__global__ void conv3_kernel(const float* __restrict__ in_, int H, int Wd,
                             const float* __restrict__ wgt,
                             const float* __restrict__ bias,
                             float* __restrict__ out, float* __restrict__ sums)
{
    int oH = (H-1)/STRIDE + 1, oW = (Wd-1)/STRIDE + 1;
    int tid = threadIdx.x;
    size_t idx = (size_t)blockIdx.x*256 + tid;
    int ow = (int)(idx % oW); size_t t = idx / oW;
    int oh = (int)(t % oH); t /= oH;
    int co = (int)(t % 3); int n = (int)(t/3);
    float w[27];
    #pragma unroll
    for (int i=0;i<27;i++) w[i] = wgt[co*27 + i];
    float acc = bias[co];
    #pragma unroll
    for (int ci=0;ci<3;ci++){
        size_t base = ((size_t)(n*3+ci))*H*Wd;
        #pragma unroll
        for (int kh=0;kh<3;kh++){
            int ih = oh*STRIDE + kh - 1;
            if (REFLECT) ih = ih<0 ? -ih : (ih>=H ? 2*H-2-ih : ih);
            #pragma unroll
            for (int kw=0;kw<3;kw++){
                int iw = ow*STRIDE + kw - 1;
                if (REFLECT) iw = iw<0 ? -iw : (iw>=Wd ? 2*Wd-2-iw : iw);
                bool ok = REFLECT || (ih>=0 && ih<H && iw>=0 && iw<Wd);
                if (ok) acc += w[(ci*3+kh)*3+kw] * in_[base + (size_t)ih*Wd + iw];
            }
        }
    }
    out[idx] = acc;
    __shared__ float red[256];
    red[tid] = acc; __syncthreads();
    for (int o=128;o>0;o>>=1){ if(tid<o) red[tid]+=red[tid+o]; __syncthreads(); }
    float blockSum = red[0]; __syncthreads();
    red[tid] = acc*acc; __syncthreads();
    for (int o=128;o>0;o>>=1){ if(tid<o) red[tid]+=red[tid+o]; __syncthreads(); }
    if (tid==0){
        int pair = n*3+co;
        atomicAdd(&sums[pair*2],   blockSum);
        atomicAdd(&sums[pair*2+1], red[0]);
    }
}

__global__ void instats_kernel(const float* __restrict__ sums, float* __restrict__ mstats, float cntInv)
{
    int i = threadIdx.x;
    if (i < 6){
        float m = sums[i*2]*cntInv;
        float v = sums[i*2+1]*cntInv - m*m;
        mstats[i*2]   = m;
        mstats[i*2+1] = rsqrtf(v + EPS);
    }
}

__global__ void inapply_kernel(const float* __restrict__ in, const float* __restrict__ mstats,
                               int planeSize, float* __restrict__ out)
{
    size_t idx = (size_t)blockIdx.x*256 + threadIdx.x;
    int pair = (int)(idx / planeSize);
    float m = mstats[pair*2], inv = mstats[pair*2+1];
    out[idx] = lrelu((in[idx]-m)*inv);
}

// -----------------------------------------------------------------------------
__global__ void up2x_kernel(const float* __restrict__ in, int H, int Wd, float* __restrict__ out)
{
    int oH = 2*H, oW = 2*Wd;
    size_t idx = (size_t)blockIdx.x*256 + threadIdx.x;
    int ow = (int)(idx % oW); size_t t = idx/oW;
    int oh = (int)(t % oH); int pl = (int)(t/oH);
    float ph = (float)oh * (float)(H-1)  / (float)(oH-1);
    float pw = (float)ow * (float)(Wd-1) / (float)(oW-1);
    int i0 = (int)ph; int i1 = min(i0+1, H-1); float fh = ph - (float)i0;
    int j0 = (int)pw; int j1 = min(j0+1, Wd-1); float fw = pw - (float)j0;
    const float* p = in + (size_t)pl*H*Wd;
    float v00=p[(size_t)i0*Wd+j0], v01=p[(size_t)i0*Wd+j1];
    float v10=p[(size_t)i1*Wd+j0], v11=p[(size_t)i1*Wd+j1];
    float v0 = v00 + (v01-v00)*fw;
    float v1 = v10 + (v11-v10)*fw;
    out[idx] = v0 + (v1-v0)*fh;
}

// -----------------------------------------------------------------------------
// MFMA correlation, 3-term bf16 split, two-pass recompute (see round-3 notes).
template<int PASS>
__global__ __launch_bounds__(256,2) void corr_mfma(
    const float* __restrict__ faT, const float* __restrict__ fbT,
    float* __restrict__ corr, float* __restrict__ SSUM,
    const float* __restrict__ INVS,
    const float* __restrict__ fc, float* __restrict__ WARP)
{
    __shared__ short lds[32768];   // 64KB: fb_hi|fb_lo|fa_hi|fa_lo, 8192 each

    int blk = blockIdx.x;
    int qb = blk & 31, pb = (blk >> 5) & 31, n = blk >> 10;
    int tid = threadIdx.x;

    const float* faB = faT + ((size_t)n*4096 + (size_t)qb*128)*64;
    const float* fbB = fbT + ((size_t)n*4096 + (size_t)pb*128)*64;
    #pragma unroll
    for (int it=0; it<8; it++){
        int cid = it*256 + tid;
        int side = cid >> 10;
        int idx  = cid & 1023;
        int r = idx & 15, c = (idx>>4)&7, g = idx>>7;
        int grow = g*16 + r;
        const float* src = (side ? faB : fbB) + grow*64 + c*8;
        float4 x0 = *(const float4*)src;
        float4 x1 = *(const float4*)(src+4);
        float xs[8] = {x0.x,x0.y,x0.z,x0.w,x1.x,x1.y,x1.z,x1.w};
        short8 h, l;
        #pragma unroll
        for (int j=0;j<8;j++){
            short hh = f2bf_s(xs[j]);
            h[j] = hh;
            l[j] = f2bf_s(xs[j] - bfs2f(hh));
        }
        int base16 = side*16384;
        *(short8*)(lds + base16 + idx*8)        = h;
        *(short8*)(lds + base16 + 8192 + idx*8) = l;
    }
    __syncthreads();

    int wave = tid >> 6, lane = tid & 63;
    int wp = wave >> 1, wq = wave & 1;
    int quad = lane >> 4, l16 = lane & 15;

    f32x4 acc[4][4];
    #pragma unroll
    for (int pt=0;pt<4;pt++)
        #pragma unroll
        for (int qt=0;qt<4;qt++)
            acc[pt][qt] = (f32x4){0.f,0.f,0.f,0.f};

    #pragma unroll
    for (int kc=0;kc<2;kc++){
        int cc = kc*4 + quad;
        bf16x8 Ah[4], Al[4], Bh[4], Bl[4];
        #pragma unroll
        for (int t4=0;t4<4;t4++){
            int offA = (((wp*4+t4)*8 + cc)*16 + l16)*8;
            Ah[t4] = (bf16x8)(*(const short8*)(lds + offA));
            Al[t4] = (bf16x8)(*(const short8*)(lds + 8192 + offA));
            int offB = 16384 + (((wq*4+t4)*8 + cc)*16 + l16)*8;
            Bh[t4] = (bf16x8)(*(const short8*)(lds + offB));
            Bl[t4] = (bf16x8)(*(const short8*)(lds + 8192 + offB));
        }
        #pragma unroll
        for (int pt=0;pt<4;pt++)
            #pragma unroll
            for (int qt=0;qt<4;qt++){
                acc[pt][qt] = mfma16(Ah[pt], Bh[qt], acc[pt][qt]);
                acc[pt][qt] = mfma16(Ah[pt], Bl[qt], acc[pt][qt]);
                acc[pt][qt] = mfma16(Al[pt], Bh[qt], acc[pt][qt]);
            }
    }

    if (PASS == 0){
        float colsum[4] = {0.f,0.f,0.f,0.f};
        #pragma unroll
        for (int pt=0;pt<4;pt++)
            #pragma unroll
            for (int qt=0;qt<4;qt++)
                #pragma unroll
                for (int i=0;i<4;i++)
                    colsum[qt] += __expf(fmaf(acc[pt][qt][i], 100.f, -64.f));
        #pragma unroll
        for (int qt=0;qt<4;qt++){
            float v = colsum[qt];
            v += __shfl_xor(v, 16);
            v += __shfl_xor(v, 32);
            if (lane < 16)
                atomicAdd(&SSUM[n*4096 + qb*128 + wq*64 + qt*16 + lane], v);
        }
    } else {
        float inv4[4];
        int qoff = n*4096 + qb*128 + wq*64 + l16;
        #pragma unroll
        for (int qt=0;qt<4;qt++) inv4[qt] = INVS[qoff + qt*16];
        float wa0[4]={0,0,0,0}, wa1[4]={0,0,0,0}, wa2[4]={0,0,0,0};
        const float* fcb = fc + (size_t)n*12288;
        float* corrN = corr + (size_t)n*4096*4096;
        #pragma unroll
        for (int pt=0;pt<4;pt++){
            #pragma unroll
            for (int i=0;i<4;i++){
                int p = pb*128 + wp*64 + pt*16 + quad*4 + i;
                float f0 = fcb[p], f1 = fcb[4096+p], f2 = fcb[8192+p];
                float* rowp = corrN + (size_t)p*4096 + qb*128 + wq*64 + l16;
                #pragma unroll
                for (int qt=0;qt<4;qt++){
                    float u = __expf(fmaf(acc[pt][qt][i], 100.f, -64.f)) * inv4[qt];
                    __builtin_nontemporal_store(u, &rowp[qt*16]);
                    wa0[qt] += f0*u; wa1[qt] += f1*u; wa2[qt] += f2*u;
                }
            }
        }
        #pragma unroll
        for (int qt=0;qt<4;qt++){
            float v0 = wa0[qt], v1 = wa1[qt], v2 = wa2[qt];
            v0 += __shfl_xor(v0,16); v0 += __shfl_xor(v0,32);
            v1 += __shfl_xor(v1,16); v1 += __shfl_xor(v1,32);
            v2 += __shfl_xor(v2,16); v2 += __shfl_xor(v2,32);
            if (lane < 16){
                int q = qb*128 + wq*64 + qt*16 + lane;
                atomicAdd(&WARP[(size_t)n*12288 +        q], v0);
                atomicAdd(&WARP[(size_t)n*12288 + 4096 + q], v1);
                atomicAdd(&WARP[(size_t)n*12288 + 8192 + q], v2);
            }
        }
    }
}

__global__ void inv_kernel(const float* __restrict__ SSUM, float* __restrict__ INVS)
{
    int i = blockIdx.x*256 + threadIdx.x;
    INVS[i] = 1.f / SSUM[i];
}

// -----------------------------------------------------------------------------
extern "C" void kernel_launch(void* const* d_in, const int* in_sizes, int n_in,
                              void* d_out, int out_size, void* d_ws, size_t ws_size,
                              hipStream_t stream)
{
    const float* fa_raw = (const float*)d_in[0];
    const float* fb_raw = (const float*)d_in[1];
    const float* fc_raw = (const float*)d_in[2];
    const float* Wa  = (const float*)d_in[3];
    const float* ba  = (const float*)d_in[4];
    const float* Wb  = (const float*)d_in[5];
    const float* bb  = (const float*)d_in[6];
    const float* Wc1 = (const float*)d_in[7];
    const float* bc1 = (const float*)d_in[8];
    const float* Wc2 = (const float*)d_in[9];
    const float* bc2 = (const float*)d_in[10];
    const float* Wu1 = (const float*)d_in[11];
    const float* bu1 = (const float*)d_in[12];
    const float* Wu2 = (const float*)d_in[13];
    const float* bu2 = (const float*)d_in[14];

    float* ws    = (float*)d_ws;
    float* FEAT  = ws;                  // 1048576 = [side][n][4096][64]
    float* CONV1 = FEAT  + 1048576;     // 98304
    float* FC64  = CONV1 + 98304;       // 24576
    float* UP1   = FC64  + 24576;       // 98304
    float* CONV2 = UP1   + 98304;       // 98304
    float* UP2   = CONV2 + 98304;       // 393216
    float* CONV3 = UP2   + 393216;      // 393216
    float* SSUM  = CONV3 + 393216;      // 8192   [zeroed]
    float* SUMS  = SSUM  + 8192;        // 48     [zeroed]
    float* FSUM  = SUMS  + 48;          // 512    [zeroed]
    float* M2SUM = FSUM  + 512;         // 256    [zeroed]
    float* WARP  = M2SUM + 256;         // 24576  [zeroed]
    float* MST   = WARP  + 24576;       // 48
    float* FST   = MST   + 48;          // 512
    float* INVS  = FST   + 512;         // 8192

    float* faT = FEAT;                  // side 0
    float* fbT = FEAT + 524288;         // side 1

    float* out_fc   = (float*)d_out;
    float* out_corr = out_fc + 393216;

    // zero the atomic accumulators (SSUM..WARP contiguous)
    hipMemsetAsync(SSUM, 0, (size_t)(8192 + 48 + 512 + 256 + 24576)*sizeof(float), stream);

    // feature extractors (both sides in one chain)
    feat_conv<<<256,256,0,stream>>>(fa_raw, fb_raw, Wa, Wb, ba, bb, FEAT, FSUM);
    fstats_kernel<<<1,256,0,stream>>>(FSUM, FST);
    feat_apply<<<512,256,0,stream>>>(FEAT, FST, M2SUM);
    feat_finish<<<64,256,0,stream>>>(FEAT, M2SUM);

    // fc path: 256->128 (reflect, s2), 128->64 (reflect, s2)
    conv3_kernel<2,true><<<384,256,0,stream>>>(fc_raw, 256,256, Wc1, bc1, CONV1, SUMS+0);
    instats_kernel<<<1,64,0,stream>>>(SUMS+0,  MST+0,  1.f/16384.f);
    inapply_kernel<<<384,256,0,stream>>>(CONV1, MST+0,  16384, CONV1);
    conv3_kernel<2,true><<<96,256,0,stream>>>(CONV1, 128,128, Wc2, bc2, FC64, SUMS+12);
    instats_kernel<<<1,64,0,stream>>>(SUMS+12, MST+12, 1.f/4096.f);
    inapply_kernel<<<96,256,0,stream>>>(FC64, MST+12, 4096, FC64);

    // correlation softmax (two-pass MFMA recompute) + fused warp
    corr_mfma<0><<<2048,256,0,stream>>>(faT, fbT, out_corr, SSUM, INVS, FC64, WARP);
    inv_kernel<<<32,256,0,stream>>>(SSUM, INVS);
    corr_mfma<1><<<2048,256,0,stream>>>(faT, fbT, out_corr, SSUM, INVS, FC64, WARP);

    // upsample block 1: 64 -> 128
    up2x_kernel<<<384,256,0,stream>>>(WARP, 64,64, UP1);
    conv3_kernel<1,false><<<384,256,0,stream>>>(UP1, 128,128, Wu1, bu1, CONV2, SUMS+24);
    instats_kernel<<<1,64,0,stream>>>(SUMS+24, MST+24, 1.f/16384.f);
    inapply_kernel<<<384,256,0,stream>>>(CONV2, MST+24, 16384, CONV2);

    // upsample block 2: 128 -> 256, final output
    up2x_kernel<<<1536,256,0,stream>>>(CONV2, 128,128, UP2);
    conv3_kernel<1,false><<<1536,256,0,stream>>>(UP2, 256,256, Wu2, bu2, CONV3, SUMS+36);
    instats_kernel<<<1,64,0,stream>>>(SUMS+36, MST+36, 1.f/65536.f);
    inapply_kernel<<<1536,256,0,stream>>>(CONV3, MST+36, 65536, out_fc);
}